// Round 8
// baseline (290.701 us; speedup 1.0000x reference)
//
#include <hip/hip_runtime.h>

#define N_EMB  65536
#define DIM    512
#define K_C    256
#define NCHUNK 16     // 16 chunks x 32 dims
#define ROWS_B 32     // rows per block
#define THETA  1.5f   // rescore gate: ~14x approx-score error sigma
#define LDSMSK 0x7FF0u  // 16B-aligned, <32KiB: no-op guard on provably-in-bounds offsets

// ws layout: cbh = frag-ordered bf16-hi centroids (256 KiB) | cnorm = float[256] (1 KiB)

typedef __attribute__((ext_vector_type(4))) float        f32x4;
typedef __attribute__((ext_vector_type(8))) __bf16       bf16x8;
typedef __attribute__((ext_vector_type(8))) short        s16x8;
typedef __attribute__((ext_vector_type(4))) unsigned int u32x4;

// ---- MFMA wrapper (rounds 1-6 verified). Primary: v8bf16; fallback v8i16.
template <class T>
__device__ inline auto mfma_bf16_t(T a, T b, f32x4 c, int)
    -> decltype(__builtin_amdgcn_mfma_f32_16x16x32_bf16(a, b, c, 0, 0, 0)) {
  return __builtin_amdgcn_mfma_f32_16x16x32_bf16(a, b, c, 0, 0, 0);
}
template <class T>
__device__ inline f32x4 mfma_bf16_t(T a, T b, f32x4 c, long) {
  return __builtin_amdgcn_mfma_f32_16x16x32_bf16(
      __builtin_bit_cast(s16x8, a), __builtin_bit_cast(s16x8, b), c, 0, 0, 0);
}
__device__ inline f32x4 MFMA(bf16x8 a, bf16x8 b, f32x4 c) {
  return mfma_bf16_t(a, b, c, 0);
}

__device__ inline unsigned umin_(unsigned a, unsigned b) { return a < b ? a : b; }
__device__ inline unsigned umax_(unsigned a, unsigned b) { return a > b ? a : b; }

// 8 fp32 -> packed bf16-hi via truncation (folds to v_perm pairs).
__device__ inline u32x4 pack8hi(const float4 a, const float4 b) {
  return (u32x4){
      (__float_as_uint(a.x) >> 16) | (__float_as_uint(a.y) & 0xFFFF0000u),
      (__float_as_uint(a.z) >> 16) | (__float_as_uint(a.w) & 0xFFFF0000u),
      (__float_as_uint(b.x) >> 16) | (__float_as_uint(b.y) & 0xFFFF0000u),
      (__float_as_uint(b.z) >> 16) | (__float_as_uint(b.w) & 0xFFFF0000u)};
}

__device__ inline u32x4 cvt8hi_rne(const float4 a, const float4 b) {
  float v[8] = {a.x, a.y, a.z, a.w, b.x, b.y, b.z, b.w};
  unsigned h[8];
#pragma unroll
  for (int i = 0; i < 8; ++i) {  // RNE for centroids (prep is cheap, keep quality)
    const unsigned u = __float_as_uint(v[i]);
    h[i] = (u + 0x7FFFu + ((u >> 16) & 1u)) >> 16;
  }
  return (u32x4){h[0] | (h[1] << 16), h[2] | (h[3] << 16),
                 h[4] | (h[5] << 16), h[6] | (h[7] << 16)};
}

// ---- prep (fused): frag-ordered bf16-hi centroids + exact fp32 norms.
// Frag element: lane L of [chunk][ct] block holds C[ct*16+(L&15)][chunk*32+(L>>4)*8+j].
__global__ void pack_centroids(const float* __restrict__ cent,
                               unsigned* __restrict__ cbh,
                               float* __restrict__ cnorm) {
  const int k    = blockIdx.x;   // centroid
  const int lane = threadIdx.x;  // 0..63, dims lane*8..+7
  const float* src = cent + (size_t)k * DIM + lane * 8;
  const float4 a = *(const float4*)src;
  const float4 b = *(const float4*)(src + 4);
  const int chunk = lane >> 2, g = lane & 3;
  ((u32x4*)cbh)[((size_t)chunk * 16 + (k >> 4)) * 64 + g * 16 + (k & 15)] =
      cvt8hi_rne(a, b);
  float s = a.x * a.x + a.y * a.y + a.z * a.z + a.w * a.w +
            b.x * b.x + b.y * b.y + b.z * b.z + b.w * b.w;
#pragma unroll
  for (int off = 32; off > 0; off >>= 1) s += __shfl_down(s, off, 64);
  if (lane == 0) cnorm[k] = s;
}

// ---- main: SEQUENTIAL E staging through swizzled LDS (the ~1.8 TB/s stripe-
// read cap was the invariant across rounds 1-6). 32 rows/block, 4 waves; wave
// pair (h) splits 256 centroids in half (q). GEMM A-frags from LDS, C-frags
// register-double-buffered from L2. Theta-gated exact rescore + gather.
__global__ __launch_bounds__(256, 3)
void neg_sampler_main(const float* __restrict__ emb,
                      const float* __restrict__ cent,
                      const unsigned* __restrict__ cbh,
                      const float* __restrict__ cnorm,
                      float* __restrict__ out) {
  __shared__ __align__(16) char     ebh[ROWS_B * 1024];  // 32 KiB bf16-hi E tile
  __shared__ __align__(16) unsigned qtop[ROWS_B][2][4];  // per-row per-half top4
  __shared__ __align__(16) unsigned ridx[ROWS_B];        // final index per row

  const int tid  = threadIdx.x;
  const int lane = tid & 63;
  const int w    = tid >> 6;
  const int h    = w >> 1;   // row-half: rows h*16..h*16+15
  const int q    = w & 1;    // ct-half: ct tiles q*8..q*8+7
  const int row0 = blockIdx.x * ROWS_B;

  // ---- stage: lane-contiguous 2-KB row reads (copy-kernel pattern),
  // bf16-hi convert, swizzled LDS write (byte ^= (row&7)<<4).
  {
    const float* tb = emb + (size_t)row0 * DIM;
    float4 va[8], vb[8];
#pragma unroll
    for (int i = 0; i < 8; ++i) {  // wave w stages rows {w, 4+w, ..., 28+w}
      const float* sp = tb + (size_t)(i * 4 + w) * DIM + lane * 8;
      va[i] = *(const float4*)sp;
      vb[i] = *(const float4*)(sp + 4);
    }
#pragma unroll
    for (int i = 0; i < 8; ++i) {
      const int r = i * 4 + w;
      const unsigned byte =
          ((unsigned)(r * 1024 + lane * 16) ^ (unsigned)((r & 7) << 4)) & LDSMSK;
      *(u32x4*)(ebh + byte) = pack8hi(va[i], vb[i]);
    }
  }

  // initial C prefetch (chunks 0,1) for this wave's 8 ct-tiles; the barrier's
  // vmcnt drain makes them ready for the GEMM loop.
  const u32x4* const cs = (const u32x4*)cbh + q * 8 * 64 + lane;
  u32x4 A[8], B[8];
#pragma unroll
  for (int i = 0; i < 8; ++i) A[i] = cs[i * 64];
#pragma unroll
  for (int i = 0; i < 8; ++i) B[i] = cs[1024 + i * 64];

  __syncthreads();

  // ---- GEMM: A-frags via swizzled ds_read_b128 (conflict-free), C dbuf'd.
  f32x4 acc[8];
#pragma unroll
  for (int i = 0; i < 8; ++i) acc[i] = (f32x4){0.f, 0.f, 0.f, 0.f};

  const unsigned ebase = (unsigned)(h * 16 * 1024);
  const unsigned elin  = (unsigned)((lane & 15) * 1024 + (lane >> 4) * 16);
  const unsigned exr   = (unsigned)((lane & 7) << 4);  // (row&7)<<4, row=lane&15

  for (int c2 = 0; c2 < NCHUNK; c2 += 2) {
    const unsigned off0 = (ebase + ((elin + c2 * 64) ^ exr)) & LDSMSK;
    const bf16x8 eh0 = *(const bf16x8*)(ebh + off0);
#pragma unroll
    for (int i = 0; i < 8; ++i)
      acc[i] = MFMA(eh0, __builtin_bit_cast(bf16x8, A[i]), acc[i]);
    const int ca = (c2 + 2) & 15;  // refill A <- chunk c2+2 (wraps harmlessly)
#pragma unroll
    for (int i = 0; i < 8; ++i) A[i] = cs[ca * 1024 + i * 64];

    const unsigned off1 = (ebase + ((elin + c2 * 64 + 64) ^ exr)) & LDSMSK;
    const bf16x8 eh1 = *(const bf16x8*)(ebh + off1);
#pragma unroll
    for (int i = 0; i < 8; ++i)
      acc[i] = MFMA(eh1, __builtin_bit_cast(bf16x8, B[i]), acc[i]);
    const int cb2 = (c2 + 3) & 15;
#pragma unroll
    for (int i = 0; i < 8; ++i) B[i] = cs[cb2 * 1024 + i * 64];
  }

  // ---- per-wave top-4 of its 128 centroids. D map: row=(lane>>4)*4+reg,
  // col=lane&15.
  const int lcol = lane & 15, lgrp = lane >> 4;
  float cnv[8];
#pragma unroll
  for (int i = 0; i < 8; ++i) cnv[i] = cnorm[(q * 8 + i) * 16 + lcol];

#pragma unroll
  for (int rg = 0; rg < 4; ++rg) {
    unsigned b0_ = 0xFFFFFFFFu, b1_ = b0_, b2_ = b0_, b3_ = b0_;
    auto ins = [&](unsigned u) {
      b3_ = umin_(b3_, umax_(b2_, u));
      b2_ = umin_(b2_, umax_(b1_, u));
      b1_ = umin_(b1_, umax_(b0_, u));
      b0_ = umin_(b0_, u);
    };
#pragma unroll
    for (int i = 0; i < 8; ++i) {
      const float s = fmaf(-2.f, acc[i][rg], cnv[i]);  // ||e||^2 drops
      ins((__float_as_uint(s) & 0xFFFFFF00u) |
          (unsigned)((q * 8 + i) * 16 + lcol));
    }
#pragma unroll
    for (int off = 1; off < 16; off <<= 1) {  // merge 16 col-lanes of the group
      const unsigned o0 = __shfl_xor(b0_, off, 64);
      const unsigned o1 = __shfl_xor(b1_, off, 64);
      const unsigned o2 = __shfl_xor(b2_, off, 64);
      const unsigned o3 = __shfl_xor(b3_, off, 64);
      ins(o0); ins(o1); ins(o2); ins(o3);
    }
    if (lcol == 0) {
      const int row = h * 16 + lgrp * 4 + rg;
      *(u32x4*)&qtop[row][q][0] = (u32x4){b0_, b1_, b2_, b3_};
    }
  }

  __syncthreads();

  // ---- merge halves + theta-gate + exact rescore; wave handles 8 rows.
  for (int rr = 0; rr < 8; ++rr) {
    const int row  = w * 8 + rr;
    const int grow = row0 + row;
    const u32x4 qa = *(const u32x4*)&qtop[row][0][0];  // broadcast reads
    const u32x4 qb = *(const u32x4*)&qtop[row][1][0];
    unsigned m0 = qa[0], m1 = qa[1], m2 = qa[2], m3 = qa[3];
    auto ins = [&](unsigned u) {  // halves are disjoint centroid sets
      m3 = umin_(m3, umax_(m2, u));
      m2 = umin_(m2, umax_(m1, u));
      m1 = umin_(m1, umax_(m0, u));
      m0 = umin_(m0, u);
    };
    ins(qb[0]); ins(qb[1]); ins(qb[2]); ins(qb[3]);

    const float a0s = __uint_as_float(m0 & 0xFFFFFF00u);
    const float a1s = __uint_as_float(m1 & 0xFFFFFF00u);
    const float a2s = __uint_as_float(m2 & 0xFFFFFF00u);
    int i2;
    if (a1s - a0s >= THETA && a2s - a1s >= THETA) {
      i2 = (int)(m1 & 0xFFu);  // provably the true 2nd-nearest
    } else {
      const int c0 = (int)(m0 & 0xFFu), c1 = (int)(m1 & 0xFFu);
      const int c2 = (int)(m2 & 0xFFu), c3 = (int)(m3 & 0xFFu);

      const float4* e4 = (const float4*)(emb + (size_t)grow * DIM) + lane * 2;
      const float4 ev0 = e4[0], ev1 = e4[1];
      auto pdot = [&](int cj) {
        const float4* c4 = (const float4*)(cent + (size_t)cj * DIM) + lane * 2;
        const float4 cv0 = c4[0], cv1 = c4[1];
        float d = ev0.x * cv0.x;
        d = fmaf(ev0.y, cv0.y, d); d = fmaf(ev0.z, cv0.z, d);
        d = fmaf(ev0.w, cv0.w, d);
        d = fmaf(ev1.x, cv1.x, d); d = fmaf(ev1.y, cv1.y, d);
        d = fmaf(ev1.z, cv1.z, d); d = fmaf(ev1.w, cv1.w, d);
        return d;
      };
      float d0 = pdot(c0), d1 = pdot(c1), d2 = pdot(c2), d3 = pdot(c3);
#pragma unroll
      for (int off = 1; off < 64; off <<= 1) {  // 4 independent chains
        d0 += __shfl_xor(d0, off, 64);
        d1 += __shfl_xor(d1, off, 64);
        d2 += __shfl_xor(d2, off, 64);
        d3 += __shfl_xor(d3, off, 64);
      }
      const float s0 = fmaf(-2.f, d0, cnorm[c0]);
      const float s1 = fmaf(-2.f, d1, cnorm[c1]);
      const float s2 = fmaf(-2.f, d2, cnorm[c2]);
      const float s3 = fmaf(-2.f, d3, cnorm[c3]);

      float v1 = s0, v2 = 3.4e38f;
      int i1 = c0; i2 = K_C;
      auto upd = [&](float s, int ci) {  // stable smaller-index tiebreak
        if (s < v1 || (s == v1 && ci < i1)) { v2 = v1; i2 = i1; v1 = s; i1 = ci; }
        else if (s < v2 || (s == v2 && ci < i2)) { v2 = s; i2 = ci; }
      };
      upd(s1, c1); upd(s2, c2); upd(s3, c3);
    }
    if (lane == 0) ridx[row] = (unsigned)i2 & 255u;
  }

  // ---- gather with 1-row lookahead (same-wave LDS RAW, no barrier needed)
  unsigned nid = ridx[w * 8] & 255u;
  const float4* sp = (const float4*)(cent + (size_t)nid * DIM) + lane * 2;
  float4 g0 = sp[0], g1 = sp[1];
  for (int rr = 0; rr < 8; ++rr) {
    const float4 o0 = g0, o1 = g1;
    if (rr + 1 < 8) {
      nid = ridx[w * 8 + rr + 1] & 255u;
      sp = (const float4*)(cent + (size_t)nid * DIM) + lane * 2;
      g0 = sp[0]; g1 = sp[1];
    }
    float4* op = (float4*)(out + (size_t)(row0 + w * 8 + rr) * DIM) + lane * 2;
    op[0] = o0;
    op[1] = o1;
  }
}

extern "C" void kernel_launch(void* const* d_in, const int* in_sizes, int n_in,
                              void* d_out, int out_size, void* d_ws, size_t ws_size,
                              hipStream_t stream) {
  (void)in_sizes; (void)n_in; (void)out_size; (void)ws_size;
  const float* emb  = (const float*)d_in[0];
  const float* cent = (const float*)d_in[1];
  // d_in[2] = batch_id, unused.
  unsigned* cbh = (unsigned*)d_ws;                     // 256 KiB frag-ordered C-hi
  float* cnorm  = (float*)((char*)d_ws + 256 * 1024);  // 1 KiB

  pack_centroids<<<K_C, 64, 0, stream>>>(cent, cbh, cnorm);
  neg_sampler_main<<<N_EMB / ROWS_B, 256, 0, stream>>>(emb, cent, cbh, cnorm,
                                                       (float*)d_out);
}